// Round 3
// baseline (142.773 us; speedup 1.0000x reference)
//
#include <hip/hip_runtime.h>
#include <hip/hip_cooperative_groups.h>

namespace cg = cooperative_groups;

#define DIM 1024
#define HEADS 16
#define BATCH 2
#define SEQ 2048
#define NBLOCK 512

// ws float layout:
// [5120,6144)  u[row] = wo @ wf
// [6144,6160)  A[h] = qa_h . ka_h
// [6160,6176)  C[h] = qb_h . ka_h
// [6176,6192)  g[h] = va_h . u_h
// [6208,6224)  c0h[h] (head-partial of the output constant; h==0 includes bf)
// [8192, 8192+64*5*1024)  partials P[c][w][d], w in {qa,qb,ka,va,vb}
#define WS_U    5120
#define WS_A    6144
#define WS_C    6160
#define WS_G    6176
#define WS_C0H  6208
#define WS_PART 8192

__global__ __launch_bounds__(256) void fused_all(
        const float* __restrict__ x,    const float* __restrict__ w_in,
        const float* __restrict__ b_in, const float* __restrict__ wq,
        const float* __restrict__ wk,   const float* __restrict__ wv,
        const float* __restrict__ wo,   const float* __restrict__ bo,
        const float* __restrict__ wf,   const float* __restrict__ bf,
        float* __restrict__ ws,         float* __restrict__ out) {
    cg::grid_group grid = cg::this_grid();
    const int bid  = blockIdx.x;
    const int tid  = threadIdx.x;
    const int wave = tid >> 6, lane = tid & 63;

    __shared__ float xs[SEQ];        // phase C
    __shared__ float red5[4][5][64]; // phase B
    __shared__ float part[HEADS];    // phase C
    __shared__ float c0s;            // phase C

    // ---------------- Phase A: weight partials ----------------
    if (bid < 256) {
        // column partials of wq/wk/wv: 64 j-chunks (16 rows) x 4 d-groups (256)
        const int dg = bid & 3, c = bid >> 2;
        const int d  = dg * 256 + tid;
        const int j0 = c * 16;
        float qa = 0.f, qb = 0.f, ka = 0.f, va = 0.f, vb = 0.f;
        #pragma unroll
        for (int j = j0; j < j0 + 16; ++j) {
            float wi = w_in[j], bi = b_in[j];
            float cq = wq[j * DIM + d];
            float ck = wk[j * DIM + d];
            float cv = wv[j * DIM + d];
            qa += wi * cq;
            qb += bi * cq;
            ka += wi * ck;
            va += wi * cv;
            vb += bi * cv;
        }
        int base = WS_PART + c * 5 * DIM + d;
        ws[base]           = qa;
        ws[base + DIM]     = qb;
        ws[base + 2 * DIM] = ka;
        ws[base + 3 * DIM] = va;
        ws[base + 4 * DIM] = vb;
    } else {
        // u[row] = wo[row,:] . wf ; one wave per row
        const int row = (bid - 256) * 4 + wave;
        float s = 0.f;
        #pragma unroll 4
        for (int e = lane; e < DIM; e += 64) s += wo[row * DIM + e] * wf[e];
        #pragma unroll
        for (int off = 32; off; off >>= 1) s += __shfl_down(s, off);
        if (lane == 0) ws[WS_U + row] = s;
    }

    grid.sync();

    // ---------------- Phase B: per-head scalar reduction ----------------
    if (bid < HEADS) {
        const int h  = bid;
        const int c4 = tid >> 6, dl = tid & 63;
        const int d  = h * 64 + dl;
        float qa = 0.f, qb = 0.f, ka = 0.f, va = 0.f, vb = 0.f;
        for (int c = c4; c < 64; c += 4) {
            int base = WS_PART + c * 5 * DIM + d;
            qa += ws[base];
            qb += ws[base + DIM];
            ka += ws[base + 2 * DIM];
            va += ws[base + 3 * DIM];
            vb += ws[base + 4 * DIM];
        }
        red5[c4][0][dl] = qa;
        red5[c4][1][dl] = qb;
        red5[c4][2][dl] = ka;
        red5[c4][3][dl] = va;
        red5[c4][4][dl] = vb;
        __syncthreads();
        if (tid < 64) {
            float fqa = red5[0][0][dl] + red5[1][0][dl] + red5[2][0][dl] + red5[3][0][dl];
            float fqb = red5[0][1][dl] + red5[1][1][dl] + red5[2][1][dl] + red5[3][1][dl];
            float fka = red5[0][2][dl] + red5[1][2][dl] + red5[2][2][dl] + red5[3][2][dl];
            float fva = red5[0][3][dl] + red5[1][3][dl] + red5[2][3][dl] + red5[3][3][dl];
            float fvb = red5[0][4][dl] + red5[1][4][dl] + red5[2][4][dl] + red5[3][4][dl];
            float u   = ws[WS_U + d];
            float pA  = fqa * fka;
            float pC  = fqb * fka;
            float pG  = fva * u;
            float pc  = fvb * u + bo[d] * wf[d];
            #pragma unroll
            for (int off = 32; off; off >>= 1) {
                pA += __shfl_down(pA, off);
                pC += __shfl_down(pC, off);
                pG += __shfl_down(pG, off);
                pc += __shfl_down(pc, off);
            }
            if (tid == 0) {
                ws[WS_A + h]   = pA;
                ws[WS_C + h]   = pC;
                ws[WS_G + h]   = pG;
                ws[WS_C0H + h] = pc + (h == 0 ? bf[0] : 0.f);
            }
        }
    }

    grid.sync();

    // ---------------- Phase C: attention over scalars ----------------
    // block -> (b, qi); handles q = qi + 256*j, j=0..7 (balanced interleave)
    const int b  = bid >> 8;
    const int qi = bid & 255;
    const float* xb = x + b * SEQ;
    for (int i = tid; i < SEQ; i += 256) xs[i] = xb[i];
    if (tid == 0) {
        float c0 = 0.f;
        #pragma unroll
        for (int i = 0; i < HEADS; ++i) c0 += ws[WS_C0H + i];
        c0s = c0;
    }
    __syncthreads();

    const int h0 = wave * 4;
    const float A0 = ws[WS_A + h0 + 0], C0 = ws[WS_C + h0 + 0], G0 = ws[WS_G + h0 + 0];
    const float A1 = ws[WS_A + h0 + 1], C1 = ws[WS_C + h0 + 1], G1 = ws[WS_G + h0 + 1];
    const float A2 = ws[WS_A + h0 + 2], C2 = ws[WS_C + h0 + 2], G2 = ws[WS_G + h0 + 2];
    const float A3 = ws[WS_A + h0 + 3], C3 = ws[WS_C + h0 + 3], G3 = ws[WS_G + h0 + 3];

    for (int j = 0; j < 8; ++j) {
        const int q = qi + j * 256;
        const float xq = xs[q];
        // logits are alpha*x_k (additive consts cancel in softmax); |alpha*x|<<88
        const float a0 = 0.125f * (A0 * xq + C0);
        const float a1 = 0.125f * (A1 * xq + C1);
        const float a2 = 0.125f * (A2 * xq + C2);
        const float a3 = 0.125f * (A3 * xq + C3);
        float n0 = 0.f, n1 = 0.f, n2 = 0.f, n3 = 0.f;
        float d0 = 0.f, d1 = 0.f, d2 = 0.f, d3 = 0.f;
        for (int k = lane; k <= q; k += 64) {
            float xk = xs[k];
            float e0 = __expf(a0 * xk);
            float e1 = __expf(a1 * xk);
            float e2 = __expf(a2 * xk);
            float e3 = __expf(a3 * xk);
            d0 += e0; n0 += e0 * xk;
            d1 += e1; n1 += e1 * xk;
            d2 += e2; n2 += e2 * xk;
            d3 += e3; n3 += e3 * xk;
        }
        #pragma unroll
        for (int off = 32; off; off >>= 1) {
            n0 += __shfl_down(n0, off); d0 += __shfl_down(d0, off);
            n1 += __shfl_down(n1, off); d1 += __shfl_down(d1, off);
            n2 += __shfl_down(n2, off); d2 += __shfl_down(d2, off);
            n3 += __shfl_down(n3, off); d3 += __shfl_down(d3, off);
        }
        if (lane == 0) {
            part[h0 + 0] = G0 * (n0 / d0);
            part[h0 + 1] = G1 * (n1 / d1);
            part[h0 + 2] = G2 * (n2 / d2);
            part[h0 + 3] = G3 * (n3 / d3);
        }
        __syncthreads();
        if (tid == 0) {
            float r = c0s;
            #pragma unroll
            for (int i = 0; i < HEADS; ++i) r += part[i];
            out[b * SEQ + q] = r;
        }
        __syncthreads();
    }
}

extern "C" void kernel_launch(void* const* d_in, const int* in_sizes, int n_in,
                              void* d_out, int out_size, void* d_ws, size_t ws_size,
                              hipStream_t stream) {
    const float* x    = (const float*)d_in[0];
    const float* w_in = (const float*)d_in[1];
    const float* b_in = (const float*)d_in[2];
    const float* wq   = (const float*)d_in[3];
    const float* wk   = (const float*)d_in[4];
    const float* wv   = (const float*)d_in[5];
    const float* wo   = (const float*)d_in[6];
    const float* bo   = (const float*)d_in[7];
    const float* wf   = (const float*)d_in[8];
    const float* bf   = (const float*)d_in[9];
    float* out = (float*)d_out;
    float* ws  = (float*)d_ws;

    void* args[] = {(void*)&x, (void*)&w_in, (void*)&b_in, (void*)&wq, (void*)&wk,
                    (void*)&wv, (void*)&wo, (void*)&bo, (void*)&wf, (void*)&bf,
                    (void*)&ws, (void*)&out};
    hipLaunchCooperativeKernel((const void*)fused_all, dim3(NBLOCK), dim3(256),
                               args, 0, stream);
}

// Round 4
// 34.394 us; speedup vs baseline: 4.1512x; 4.1512x over previous
//
#include <hip/hip_runtime.h>

#define DIM 1024
#define HEADS 16
#define BATCH 2
#define SEQ 2048
#define NCHUNK 64          // j-chunks for col partials (16 rows each)

// ws float layout:
// [5120,6144)  u[row] = wo @ wf
// [6144,6160)  A[h]   = qa_h . ka_h
// [6160,6176)  C[h]   = qb_h . ka_h
// [6176,6192)  G[h]   = va_h . u_h
// [6192,6208)  c0h[h] head-partial of output constant (h==0 includes bf)
// [8192, 8192 + NCHUNK*5*1024)  partials P[c][w][d], w in {qa,qb,ka,va,vb}
#define WS_U    5120
#define WS_A    6144
#define WS_C    6160
#define WS_G    6176
#define WS_C0H  6192
#define WS_PART 8192

// grid 320: [0,64) col-partial blocks (16 rows each, full 1024 d via float4);
//           [64,320) wo@wf row blocks (4 rows each, one wave per row)
__global__ __launch_bounds__(256) void k1_precompute(
        const float* __restrict__ w_in, const float* __restrict__ b_in,
        const float* __restrict__ wq,   const float* __restrict__ wk,
        const float* __restrict__ wv,   const float* __restrict__ wo,
        const float* __restrict__ wf,   float* __restrict__ ws) {
    const int bid = blockIdx.x;
    const int tid = threadIdx.x;
    if (bid < NCHUNK) {
        const int j0 = bid * 16;
        float4 qa = {0,0,0,0}, qb = {0,0,0,0}, ka = {0,0,0,0};
        float4 va = {0,0,0,0}, vb = {0,0,0,0};
        #pragma unroll
        for (int j = j0; j < j0 + 16; ++j) {
            const float wi = w_in[j], bi = b_in[j];
            const float4 cq = ((const float4*)(wq + j * DIM))[tid];
            const float4 ck = ((const float4*)(wk + j * DIM))[tid];
            const float4 cv = ((const float4*)(wv + j * DIM))[tid];
            qa.x += wi * cq.x; qa.y += wi * cq.y; qa.z += wi * cq.z; qa.w += wi * cq.w;
            qb.x += bi * cq.x; qb.y += bi * cq.y; qb.z += bi * cq.z; qb.w += bi * cq.w;
            ka.x += wi * ck.x; ka.y += wi * ck.y; ka.z += wi * ck.z; ka.w += wi * ck.w;
            va.x += wi * cv.x; va.y += wi * cv.y; va.z += wi * cv.z; va.w += wi * cv.w;
            vb.x += bi * cv.x; vb.y += bi * cv.y; vb.z += bi * cv.z; vb.w += bi * cv.w;
        }
        float4* base = (float4*)(ws + WS_PART + bid * 5 * DIM);
        base[tid]             = qa;
        base[256 + tid]       = qb;
        base[2 * 256 + tid]   = ka;
        base[3 * 256 + tid]   = va;
        base[4 * 256 + tid]   = vb;
    } else {
        const int wave = tid >> 6, lane = tid & 63;
        const int row = (bid - NCHUNK) * 4 + wave;
        const float4* wo4 = (const float4*)(wo + row * DIM);
        const float4* wf4 = (const float4*)wf;
        float s = 0.f;
        #pragma unroll
        for (int e = lane; e < 256; e += 64) {
            float4 a = wo4[e], b = wf4[e];
            s += a.x * b.x + a.y * b.y + a.z * b.z + a.w * b.w;
        }
        #pragma unroll
        for (int off = 32; off; off >>= 1) s += __shfl_down(s, off);
        if (lane == 0) ws[WS_U + row] = s;
    }
}

// 16 blocks (one per head) x 256 threads (4 waves split the chunks)
__global__ __launch_bounds__(256) void k2_combine(
        const float* __restrict__ bo, const float* __restrict__ wf,
        const float* __restrict__ bf, float* __restrict__ ws) {
    const int h = blockIdx.x;
    const int tid = threadIdx.x;
    const int c4 = tid >> 6, dl = tid & 63;
    const int d = h * 64 + dl;
    float qa = 0.f, qb = 0.f, ka = 0.f, va = 0.f, vb = 0.f;
    for (int c = c4; c < NCHUNK; c += 4) {
        const float* base = ws + WS_PART + c * 5 * DIM + d;
        qa += base[0];
        qb += base[DIM];
        ka += base[2 * DIM];
        va += base[3 * DIM];
        vb += base[4 * DIM];
    }
    __shared__ float red5[4][5][64];
    red5[c4][0][dl] = qa;
    red5[c4][1][dl] = qb;
    red5[c4][2][dl] = ka;
    red5[c4][3][dl] = va;
    red5[c4][4][dl] = vb;
    __syncthreads();
    if (tid < 64) {
        float fqa = red5[0][0][dl] + red5[1][0][dl] + red5[2][0][dl] + red5[3][0][dl];
        float fqb = red5[0][1][dl] + red5[1][1][dl] + red5[2][1][dl] + red5[3][1][dl];
        float fka = red5[0][2][dl] + red5[1][2][dl] + red5[2][2][dl] + red5[3][2][dl];
        float fva = red5[0][3][dl] + red5[1][3][dl] + red5[2][3][dl] + red5[3][3][dl];
        float fvb = red5[0][4][dl] + red5[1][4][dl] + red5[2][4][dl] + red5[3][4][dl];
        const float u = ws[WS_U + d];
        float pA = fqa * fka;
        float pC = fqb * fka;
        float pG = fva * u;
        float pc = fvb * u + bo[d] * wf[d];
        #pragma unroll
        for (int off = 32; off; off >>= 1) {
            pA += __shfl_down(pA, off);
            pC += __shfl_down(pC, off);
            pG += __shfl_down(pG, off);
            pc += __shfl_down(pc, off);
        }
        if (tid == 0) {
            ws[WS_A + h]   = pA;
            ws[WS_C + h]   = pC;
            ws[WS_G + h]   = pG;
            ws[WS_C0H + h] = pc + (h == 0 ? bf[0] : 0.f);
        }
    }
}

// one block per (b,q); 4 waves, each wave owns 4 heads (one LDS read feeds 4 exps)
__global__ __launch_bounds__(256) void k3_attn(const float* __restrict__ x,
                                               const float* __restrict__ ws,
                                               float* __restrict__ out) {
    const int bid = blockIdx.x;
    const int b = bid >> 11;                   // SEQ = 2048
    const int q = (SEQ - 1) - (bid & (SEQ - 1)); // big-q blocks dispatch first
    const int tid = threadIdx.x;
    const int w = tid >> 6, lane = tid & 63;

    __shared__ float xs[SEQ];
    __shared__ float part[HEADS];
    __shared__ float c0s;

    const float* xb = x + b * SEQ;
    for (int i = tid; i <= q; i += 256) xs[i] = xb[i];
    if (tid == 0) {
        float c0 = 0.f;
        #pragma unroll
        for (int i = 0; i < HEADS; ++i) c0 += ws[WS_C0H + i];
        c0s = c0;
    }
    __syncthreads();

    const float xq = xs[q];
    const int h0 = w * 4;
    // logits are alpha*x_k (additive consts cancel in softmax); |alpha*x| << 88
    const float a0 = 0.125f * (ws[WS_A + h0 + 0] * xq + ws[WS_C + h0 + 0]);
    const float a1 = 0.125f * (ws[WS_A + h0 + 1] * xq + ws[WS_C + h0 + 1]);
    const float a2 = 0.125f * (ws[WS_A + h0 + 2] * xq + ws[WS_C + h0 + 2]);
    const float a3 = 0.125f * (ws[WS_A + h0 + 3] * xq + ws[WS_C + h0 + 3]);

    float n0 = 0.f, n1 = 0.f, n2 = 0.f, n3 = 0.f;
    float d0 = 0.f, d1 = 0.f, d2 = 0.f, d3 = 0.f;
    for (int k = lane; k <= q; k += 64) {
        const float xk = xs[k];
        const float e0 = __expf(a0 * xk);
        const float e1 = __expf(a1 * xk);
        const float e2 = __expf(a2 * xk);
        const float e3 = __expf(a3 * xk);
        d0 += e0; n0 += e0 * xk;
        d1 += e1; n1 += e1 * xk;
        d2 += e2; n2 += e2 * xk;
        d3 += e3; n3 += e3 * xk;
    }
    #pragma unroll
    for (int off = 32; off; off >>= 1) {
        n0 += __shfl_down(n0, off); d0 += __shfl_down(d0, off);
        n1 += __shfl_down(n1, off); d1 += __shfl_down(d1, off);
        n2 += __shfl_down(n2, off); d2 += __shfl_down(d2, off);
        n3 += __shfl_down(n3, off); d3 += __shfl_down(d3, off);
    }
    if (lane == 0) {
        part[h0 + 0] = ws[WS_G + h0 + 0] * (n0 / d0);
        part[h0 + 1] = ws[WS_G + h0 + 1] * (n1 / d1);
        part[h0 + 2] = ws[WS_G + h0 + 2] * (n2 / d2);
        part[h0 + 3] = ws[WS_G + h0 + 3] * (n3 / d3);
    }
    __syncthreads();
    if (tid == 0) {
        float r = c0s;
        #pragma unroll
        for (int i = 0; i < HEADS; ++i) r += part[i];
        out[b * SEQ + q] = r;
    }
}

extern "C" void kernel_launch(void* const* d_in, const int* in_sizes, int n_in,
                              void* d_out, int out_size, void* d_ws, size_t ws_size,
                              hipStream_t stream) {
    const float* x    = (const float*)d_in[0];
    const float* w_in = (const float*)d_in[1];
    const float* b_in = (const float*)d_in[2];
    const float* wq   = (const float*)d_in[3];
    const float* wk   = (const float*)d_in[4];
    const float* wv   = (const float*)d_in[5];
    const float* wo   = (const float*)d_in[6];
    const float* bo   = (const float*)d_in[7];
    const float* wf   = (const float*)d_in[8];
    const float* bf   = (const float*)d_in[9];
    float* out = (float*)d_out;
    float* ws  = (float*)d_ws;

    k1_precompute<<<NCHUNK + 256, 256, 0, stream>>>(w_in, b_in, wq, wk, wv, wo, wf, ws);
    k2_combine<<<HEADS, 256, 0, stream>>>(bo, wf, bf, ws);
    k3_attn<<<BATCH * SEQ, 256, 0, stream>>>(x, ws, out);
}